// Round 6
// baseline (715.300 us; speedup 1.0000x reference)
//
#include <hip/hip_runtime.h>
#include <math.h>
#include <stdint.h>

// ---------------------------------------------------------------------------
// Muskingum-Cunge tree routing, spatially-pipelined persistent kernel, v16.
//
// v15 post-mortem: PIN_MEM regressed (607 vs v14's 556) and VGPR only 76 --
// the VGPR=64 "sunk prefetch" theory was wrong: 64 regs is consistent with a
// GOOD schedule (bank values die progressively; arriving prefetches recycle
// their registers). The clobbers only removed scheduling freedom.
//
// v16 accounting: 652cy/step (v14) vs ~460-480 floor (16 trans/step at
// ~16cy issue + chain VALU + glue; VALUBusy 62% renormalized matches).
// Residual ~120cy/step is STALL. Consumer-side tag staleness self-heals
// (one stall grows the lag permanently; equal periods keep it fresh).
// Producer-side back-pressure does NOT: lead grows monotonically until
// pinned at the ring cap (slotsB=8); once pinned, the producer needs the
// consumer's batch-(bi-8) completion published BEFORE its store section
// every batch -- but the consumer publishes at END-of-body, so the
// producer's head poll chronically misses and spins (~500-1000cy/batch).
//
// v16 change (v14 structure restored exactly, one change):
//   progress publish moved from end-of-body to IMMEDIATELY AFTER the tag
//   scan -- the ring slot is dead once its data is secured in registers.
//   Publish ordered on the scan result (empty-asm dep on mism) so it can
//   never hoist above the scan loads (else producer could overwrite the
//   slot mid-scan -> tag-equality deadlock). This publishes a full body
//   (~10k cy) earlier, satisfying the producer's non-blocking head poll
//   and killing the pinned-cap spin.
// ---------------------------------------------------------------------------

#define N_LEVELS   14
#define T_STEPS    2048
#define NR_TOTAL   16383
#define DT_SUB_F   21600.0f
#define EPS_F      1e-6f
#define NBLOCKS    71
#define CTR_STRIDE 8             // ints per wave counter (32 B apart)
#define RING_BYTE_OFF 16384

__device__ __constant__ int kSize[N_LEVELS] = {8192,4096,2048,1024,512,256,128,64,32,16,8,4,2,1};
__device__ __constant__ int kEpb [N_LEVELS] = {256,256,256,256,256,256,128,64,32,16,8,4,2,1};
__device__ __constant__ int kBlkStart[N_LEVELS+1] = {0,32,48,56,60,62,63,64,65,66,67,68,69,70,71};
__device__ __constant__ int kOffL[N_LEVELS] = {0,8192,12288,14336,15360,15872,16128,16256,16320,16352,16368,16376,16380,16382};
// pair-sum entries before level l
__device__ __constant__ int kOffH[N_LEVELS-1] = {0,4096,6144,7168,7680,7936,8064,8128,8160,8176,8184,8188,8190};

#if __has_builtin(__builtin_amdgcn_exp2f)
#define FAST_EXP2(x) __builtin_amdgcn_exp2f(x)
#else
#define FAST_EXP2(x) exp2f(x)
#endif
#if __has_builtin(__builtin_amdgcn_logf)
#define FAST_LOG2(x) __builtin_amdgcn_logf(x)
#else
#define FAST_LOG2(x) log2f(x)
#endif
#if __has_builtin(__builtin_amdgcn_rcpf)
#define FAST_RCP(x) __builtin_amdgcn_rcpf(x)
#else
#define FAST_RCP(x) (1.0f/(x))
#endif

// pair sum of lanes (2k,2k+1) via DPP quad_perm [1,0,3,2]: pure VALU, no LDS.
__device__ __forceinline__ float pair_sum(float x) {
    int yi = __builtin_amdgcn_update_dpp(0, __float_as_int(x),
                                         0xB1 /*quad_perm 1,0,3,2*/,
                                         0xF, 0xF, true);
    return x + __int_as_float(yi);
}

#define ATOMIC_LD_RLX(p)   __hip_atomic_load((p), __ATOMIC_RELAXED, __HIP_MEMORY_SCOPE_AGENT)
#define ATOMIC_ST_RLX(p,v) __hip_atomic_store((p), (v), __ATOMIC_RELAXED, __HIP_MEMORY_SCOPE_AGENT)

// One math step (fully unrolled, constant j). References enclosing-scope
// Q, Ip, prodMask, hasCons, per-reach constants; writes qs[j].
#define MC_MATH_LOOP(J0, J1, latC, pendC)                                      \
      _Pragma("unroll")                                                        \
      for (int j = (J0); j < (J1); ++j) {                                      \
        float inflow = latC[j] +                                               \
            __uint_as_float((unsigned)pendC[j] & prodMask);                    \
                                                                               \
        float q = Q;                                                           \
        const float ti  = inflow;                                              \
        const float t13 = ti * (1.0f/3.0f);                                    \
        const float t23 = ti * (2.0f/3.0f);                                    \
        const float dti = (2.0f * DT_SUB_F) * ti;                              \
        {   /* substep 0: io = Ip */                                           \
          const float io = Ip;                                                 \
          float Qref = fmaxf(fmaf(io + q, 1.0f/3.0f, t13), EPS_F);             \
          float lq   = FAST_LOG2(Qref);                                        \
          float K2   = FAST_EXP2(fmaf(eK, lq, cK2));                           \
          float t    = FAST_EXP2(fmaf(et, lq, ct));                            \
          float X    = fmaxf(0.5f - t, 0.0f);                                  \
          float KX2  = K2 * X;                                                 \
          float A    = K2 - KX2;                                               \
          float rD   = FAST_RCP(A + DT_SUB_F);                                 \
          float num  = fmaf(A, q, fmaf(KX2, io - ti,                           \
                             DT_SUB_F * ((ti + io) - q)));                     \
          q = fmaxf(num * rD, 0.0f);                                           \
        }                                                                      \
        _Pragma("unroll")                                                      \
        for (int s = 1; s < 4; ++s) {   /* substeps 1..3: io == inflow */      \
          float Qref = fmaxf(fmaf(q, 1.0f/3.0f, t23), EPS_F);                  \
          float lq   = FAST_LOG2(Qref);                                        \
          float K2   = FAST_EXP2(fmaf(eK, lq, cK2));                           \
          float t    = FAST_EXP2(fmaf(et, lq, ct));                            \
          float X    = fmaxf(0.5f - t, 0.0f);                                  \
          float A    = K2 - K2 * X;                                            \
          float rD   = FAST_RCP(A + DT_SUB_F);                                 \
          float num  = fmaf(A, q, fmaf(-DT_SUB_F, q, dti)); /* +DT*(2ti-q) */  \
          q = fmaxf(num * rD, 0.0f);                                           \
        }                                                                      \
        Q = q; Ip = inflow;                                                    \
                                                                               \
        float ps = pair_sum(q);          /* DPP, branchless, always */         \
        qs[j] = hasCons ? ps : q;        /* uniform select */                  \
      }

// ---------------------------------------------------------------------------
// One batch body (textual macro; banks substitute as plain array names).
// ---------------------------------------------------------------------------
#define MC_BODY(BI, latC, pendC, latN, pendN)                                  \
  {                                                                            \
    const int bi = (BI);                                                       \
    const int tb = bi * B;                                                     \
    /* clamped next-batch time base: last body harmlessly re-reads last batch*/\
    const int tbn = (tb + B < T_STEPS) ? (tb + B) : (T_STEPS - B);             \
                                                                               \
    /* ---- poll consumer progress early (non-blocking) ---- */                \
    int pfCons = -0x40000000;                                                  \
    const int need = (bi - slotsB + 1) * B;                                    \
    if (hasCons && bi >= slotsB && cachedCons < need) {                        \
      int v0 = ATOMIC_LD_RLX(&prog[c0i]);                                      \
      int v1 = (c1i == c0i) ? v0 : ATOMIC_LD_RLX(&prog[c1i]);                  \
      pfCons = (v0 < v1) ? v0 : v1;                                            \
    }                                                                          \
                                                                               \
    /* ---- verify CURRENT batch tags (prefetched mid-previous body) ----- */  \
    /* Steady state: fresh -> scan passes, zero reloads. Backstop: whole- */   \
    /* batch parallel reload + rescan (one round-trip per retry).         */   \
    unsigned mism = 0;                                                         \
    if (hasProd) {                                                             \
      const unsigned long long* upC =                                          \
          ringUp + (size_t)(bi & sBm1) * upSlotSz + e;                         \
      _Pragma("unroll")                                                        \
      for (int j = 0; j < B; ++j)                                              \
        mism |= ((unsigned)(pendC[j] >> 32) ^ (unsigned)(tb + j + 1));         \
      int spin = 0;                                                            \
      while (__builtin_expect(mism != 0u, 0)) {                                \
        _Pragma("unroll")                                                      \
        for (int j = 0; j < B; ++j)                                            \
          pendC[j] = ATOMIC_LD_RLX(upC + (size_t)j * size);                    \
        mism = 0;                                                              \
        _Pragma("unroll")                                                      \
        for (int j = 0; j < B; ++j)                                            \
          mism |= ((unsigned)(pendC[j] >> 32) ^ (unsigned)(tb + j + 1));       \
        if (mism && (((++spin) & 15) == 0)) __builtin_amdgcn_s_sleep(1);       \
      }                                                                        \
    }                                                                          \
                                                                               \
    /* ---- EARLY publish: slot bi is dead once its data is in registers. */   \
    /* Ordered on the scan result (mism) so the store can never hoist     */   \
    /* above the scan loads (would allow mid-scan overwrite -> deadlock). */   \
    if (waveLead) {                                                            \
      int pubv = tb + B;                                                       \
      unsigned dep = mism;                                                     \
      __asm__ volatile("" : "+v"(pubv) : "v"(dep));                            \
      ATOMIC_ST_RLX(&prog[myCtr], pubv);                                       \
    }                                                                          \
                                                                               \
    /* ================= giant branchless BB, half 0 ================= */      \
    float qs[B];                                                               \
    {                                                                          \
      const size_t nbBase = (size_t)tbn * NR_TOTAL + (size_t)rr;               \
      _Pragma("unroll")                                                        \
      for (int j = 0; j < B; ++j)                                              \
        latN[j] = lat[nbBase + (size_t)j * NR_TOTAL];                          \
      MC_MATH_LOOP(0, B/2, latC, pendC)                                        \
                                                                               \
      /* ---- mid-body: prefetch NEXT batch ring (fresh in steady state; */    \
      /* ~B/2 steps of math ahead of use covers the MALL flight).        */    \
      /* Unconditional: level-0 reads are harmless in-bounds garbage,    */    \
      /* masked by prodMask; keeps this whole region one BB.             */    \
      {                                                                        \
        const unsigned long long* upN =                                        \
            ringUp + (size_t)((bi + 1) & sBm1) * upSlotSz + e;                 \
        _Pragma("unroll")                                                      \
        for (int j = 0; j < B; ++j)                                            \
          pendN[j] = ATOMIC_LD_RLX(upN + (size_t)j * size);                    \
      }                                                                        \
                                                                               \
      MC_MATH_LOOP(B/2, B, latC, pendC)                                        \
    }                                                                          \
    /* ================= end giant BB ================= */                     \
                                                                               \
    /* ---- back-pressure, then store the batch ---- */                        \
    if (hasCons) {                                                             \
      if (bi >= slotsB && cachedCons < need) {                                 \
        if (pfCons >= need) {                                                  \
          cachedCons = pfCons;                                                 \
        } else {                                                               \
          int spin = 0;                                                        \
          for (;;) {                                                           \
            int v0 = ATOMIC_LD_RLX(&prog[c0i]);                                \
            int v1 = (c1i == c0i) ? v0 : ATOMIC_LD_RLX(&prog[c1i]);            \
            int m  = (v0 < v1) ? v0 : v1;                                      \
            if (m >= need) { cachedCons = m; break; }                          \
            if (((++spin) & 63) == 0) __builtin_amdgcn_s_sleep(1);             \
          }                                                                    \
        }                                                                      \
      }                                                                        \
      if (validT && ((tid & 1) == 0)) {                                        \
        unsigned long long* st =                                               \
            ringMy + (size_t)(bi & sBm1) * mySlotSz + (e >> 1);                \
        _Pragma("unroll")                                                      \
        for (int j = 0; j < B; ++j) {                                          \
          unsigned long long v =                                               \
              ((unsigned long long)(unsigned)(tb + j + 1) << 32) |             \
              (unsigned long long)__float_as_uint(qs[j]);                      \
          ATOMIC_ST_RLX(st + (size_t)j * halfSize, v);                         \
        }                                                                      \
      }                                                                        \
    } else if (tid == 0) {                                                     \
      _Pragma("unroll")                                                        \
      for (int j = 0; j < B; ++j)                                              \
        out[tb + j] = qs[j];                                                   \
    }                                                                          \
  }

template<int B>
__global__ __launch_bounds__(256, 1)
void mc_route_pipe16(const float* __restrict__ lat,
                     const float* __restrict__ logn,
                     const float* __restrict__ len,
                     const float* __restrict__ slope,
                     const float* __restrict__ wcoef,
                     const float* __restrict__ wexp,
                     const float* __restrict__ dcoef,
                     const float* __restrict__ dexp,
                     float* __restrict__ out,
                     int* __restrict__ prog,
                     unsigned long long* __restrict__ ring,
                     int slotsB)
{
    const int bid = blockIdx.x;
    const int tid = threadIdx.x;

    int lvl = 0;
#pragma unroll
    for (int l = 1; l < N_LEVELS; ++l)
        if (bid >= kBlkStart[l]) lvl = l;

    const int  bl     = bid - kBlkStart[lvl];
    const int  epb    = kEpb[lvl];
    const int  size   = kSize[lvl];
    const bool validT = (tid < epb);
    const int  e      = bl * epb + (validT ? tid : (epb - 1));
    const int  rr     = kOffL[lvl] + e;

    // -------- per-reach constants (chain-fused form, v5-verified) ----------
    const float dx      = len[rr];
    const float S       = slope[rr];
    const float sqrtS_n = sqrtf(S) * expf(-logn[rr]);        // sqrt(S)/n
    const float de23    = 0.66666667f * dexp[rr];
    const float l2dc    = log2f(dcoef[rr]);
    const float l2base  = log2f(0.6f / sqrtS_n) - 0.66666667f * l2dc;
    const float eK      = -de23;
    const float cK2     = log2f(2.0f * dx) + l2base;
    const float et      = 1.0f - de23 - wexp[rr];
    const float ct      = log2f(0.5f / (S * dx)) + l2base - log2f(wcoef[rr]);

    // -------- pipeline wiring ----------------------------------------------
    const bool hasProd = (lvl > 0);
    const bool hasCons = (lvl < N_LEVELS - 1);
    const unsigned prodMask = hasProd ? 0xFFFFFFFFu : 0u;
    const int  SBB     = slotsB * B;
    const int  sBm1    = slotsB - 1;
    const unsigned long long* ringUp = hasProd ? ring + (size_t)kOffH[lvl-1] * SBB : ring;
    unsigned long long*       ringMy = hasCons ? ring + (size_t)kOffH[lvl]   * SBB : ring;
    const int halfSize = size >> 1;
    const int upSlotSz = size * B;
    const int mySlotSz = halfSize * B;

    int c0i = 0, c1i = 0;
    if (hasCons) {
        const int ceLo = (bl * epb) >> 1;
        const int ceHi = ((bl + 1) * epb - 1) >> 1;
        const int epbN = kEpb[lvl+1];
        const int cb   = kBlkStart[lvl+1] + ceLo / epbN;
        const int le0  = ceLo - (ceLo / epbN) * epbN;
        const int le1  = ceHi - (ceHi / epbN) * epbN;
        c0i = (cb * 4 + (le0 >> 6)) * CTR_STRIDE;
        c1i = (cb * 4 + (le1 >> 6)) * CTR_STRIDE;
    }
    const int  myCtr    = (bid * 4 + (tid >> 6)) * CTR_STRIDE;
    const bool waveLead = ((tid & 63) == 0);

    float Q = 0.0f, Ip = 0.0f;
    int cachedCons = -0x40000000;

    float latA[B], latB[B];
    unsigned long long pendA[B], pendB[B];

    // -------- prologue: load batch 0 into bank A ---------------------------
#pragma unroll
    for (int j = 0; j < B; ++j)
        latA[j] = lat[(size_t)j * NR_TOTAL + rr];
    if (hasProd) {
#pragma unroll
        for (int j = 0; j < B; ++j)
            pendA[j] = ATOMIC_LD_RLX(ringUp + (size_t)j * size + e);
    } else {
#pragma unroll
        for (int j = 0; j < B; ++j) { pendA[j] = 0; pendB[j] = 0; }
    }

    // 2x-unrolled batch loop, ping-pong banks (no swap movs, no pointers)
    for (int bb = 0; bb < T_STEPS / B; bb += 2) {
        MC_BODY(bb,     latA, pendA, latB, pendB);
        MC_BODY(bb + 1, latB, pendB, latA, pendA);
    }
}

extern "C" void kernel_launch(void* const* d_in, const int* in_sizes, int n_in,
                              void* d_out, int out_size, void* d_ws, size_t ws_size,
                              hipStream_t stream) {
    const float* lat   = (const float*)d_in[0];
    const float* logn  = (const float*)d_in[1];
    const float* len   = (const float*)d_in[2];
    const float* slope = (const float*)d_in[3];
    const float* wc    = (const float*)d_in[4];
    const float* we    = (const float*)d_in[5];
    const float* dc    = (const float*)d_in[6];
    const float* de    = (const float*)d_in[7];
    float* out = (float*)d_out;

    int* prog = (int*)d_ws;
    unsigned long long* ring = (unsigned long long*)((char*)d_ws + RING_BYTE_OFF);

    auto needBytes = [](int Bv, int Sv) {
        return (size_t)RING_BYTE_OFF + (size_t)8191 * 8 * Bv * Sv;
    };

    if (needBytes(16, 8) <= ws_size) {
        mc_route_pipe16<16><<<NBLOCKS, 256, 0, stream>>>(lat, logn, len, slope, wc, we, dc, de,
                                                         out, prog, ring, 8);
    } else if (needBytes(16, 4) <= ws_size) {
        mc_route_pipe16<16><<<NBLOCKS, 256, 0, stream>>>(lat, logn, len, slope, wc, we, dc, de,
                                                         out, prog, ring, 4);
    } else if (needBytes(16, 2) <= ws_size) {
        mc_route_pipe16<16><<<NBLOCKS, 256, 0, stream>>>(lat, logn, len, slope, wc, we, dc, de,
                                                         out, prog, ring, 2);
    } else if (needBytes(8, 4) <= ws_size) {
        mc_route_pipe16<8><<<NBLOCKS, 256, 0, stream>>>(lat, logn, len, slope, wc, we, dc, de,
                                                        out, prog, ring, 4);
    } else {
        mc_route_pipe16<8><<<NBLOCKS, 256, 0, stream>>>(lat, logn, len, slope, wc, we, dc, de,
                                                        out, prog, ring, 2);
    }
}

// Round 7
// 696.751 us; speedup vs baseline: 1.0266x; 1.0266x over previous
//
#include <hip/hip_runtime.h>
#include <math.h>
#include <stdint.h>

// ---------------------------------------------------------------------------
// Muskingum-Cunge tree routing, spatially-pipelined persistent kernel, v17.
//
// v16 post-mortem: early-publish null (572 vs v14's 556) -> producer
// back-pressure was NOT the stall. Both handoff theories exhausted; the
// protocol is clean. Floor accounting: 652cy/step measured vs ~600cy/step
// dependent-chain floor (per substep: fma,fmax,LOG2,fma,EXP2(t),EXP2(K2,
// issue-stacked),fmax,mul,sub,add,RCP,mul,fmax; trans dep ~28cy = 16 issue
// + 12 latency; VALUBusy 62% renormalized matches 16 trans x 16cy issue).
//
// v17 = EXACT v14 structure (best: 556us) + bit-exact issue-order fixes:
//   (1) t = exp2(...) issued BEFORE K2 = exp2(...): the chain runs through
//       t (t->X->KX2->A->D->rcp); K2 is needed one VALU later. Two parallel
//       trans still serialize their 16cy ISSUE, so putting t first delivers
//       it ~16cy earlier: ~10cy/substep -> ~40cy/step (~6%).
//   (2) hoist off-chain terms (inner fma, io-ti, (ti+io)-q) ahead of log2
//       so they fill its issue shadow. Same instructions, same rounding --
//       bit-exact, absmax stays 0.
// ---------------------------------------------------------------------------

#define N_LEVELS   14
#define T_STEPS    2048
#define NR_TOTAL   16383
#define DT_SUB_F   21600.0f
#define EPS_F      1e-6f
#define NBLOCKS    71
#define CTR_STRIDE 8             // ints per wave counter (32 B apart)
#define RING_BYTE_OFF 16384

__device__ __constant__ int kSize[N_LEVELS] = {8192,4096,2048,1024,512,256,128,64,32,16,8,4,2,1};
__device__ __constant__ int kEpb [N_LEVELS] = {256,256,256,256,256,256,128,64,32,16,8,4,2,1};
__device__ __constant__ int kBlkStart[N_LEVELS+1] = {0,32,48,56,60,62,63,64,65,66,67,68,69,70,71};
__device__ __constant__ int kOffL[N_LEVELS] = {0,8192,12288,14336,15360,15872,16128,16256,16320,16352,16368,16376,16380,16382};
// pair-sum entries before level l
__device__ __constant__ int kOffH[N_LEVELS-1] = {0,4096,6144,7168,7680,7936,8064,8128,8160,8176,8184,8188,8190};

#if __has_builtin(__builtin_amdgcn_exp2f)
#define FAST_EXP2(x) __builtin_amdgcn_exp2f(x)
#else
#define FAST_EXP2(x) exp2f(x)
#endif
#if __has_builtin(__builtin_amdgcn_logf)
#define FAST_LOG2(x) __builtin_amdgcn_logf(x)
#else
#define FAST_LOG2(x) log2f(x)
#endif
#if __has_builtin(__builtin_amdgcn_rcpf)
#define FAST_RCP(x) __builtin_amdgcn_rcpf(x)
#else
#define FAST_RCP(x) (1.0f/(x))
#endif

// pair sum of lanes (2k,2k+1) via DPP quad_perm [1,0,3,2]: pure VALU, no LDS.
__device__ __forceinline__ float pair_sum(float x) {
    int yi = __builtin_amdgcn_update_dpp(0, __float_as_int(x),
                                         0xB1 /*quad_perm 1,0,3,2*/,
                                         0xF, 0xF, true);
    return x + __int_as_float(yi);
}

#define ATOMIC_LD_RLX(p)   __hip_atomic_load((p), __ATOMIC_RELAXED, __HIP_MEMORY_SCOPE_AGENT)
#define ATOMIC_ST_RLX(p,v) __hip_atomic_store((p), (v), __ATOMIC_RELAXED, __HIP_MEMORY_SCOPE_AGENT)

// One math step (fully unrolled, constant j). References enclosing-scope
// Q, Ip, prodMask, hasCons, per-reach constants; writes qs[j].
// Issue-order tuned: off-chain terms before log2; t-exp2 before K2-exp2.
#define MC_MATH_LOOP(J0, J1, latC, pendC)                                      \
      _Pragma("unroll")                                                        \
      for (int j = (J0); j < (J1); ++j) {                                      \
        float inflow = latC[j] +                                               \
            __uint_as_float((unsigned)pendC[j] & prodMask);                    \
                                                                               \
        float q = Q;                                                           \
        const float ti  = inflow;                                              \
        const float t13 = ti * (1.0f/3.0f);                                    \
        const float t23 = ti * (2.0f/3.0f);                                    \
        const float dti = (2.0f * DT_SUB_F) * ti;                              \
        {   /* substep 0: io = Ip */                                           \
          const float io    = Ip;                                              \
          const float iomti = io - ti;              /* off-chain, pre-log2 */  \
          const float inn0  = DT_SUB_F * ((ti + io) - q);   /* off-chain */    \
          float Qref = fmaxf(fmaf(io + q, 1.0f/3.0f, t13), EPS_F);             \
          float lq   = FAST_LOG2(Qref);                                        \
          float t    = FAST_EXP2(fmaf(et, lq, ct));  /* issue FIRST: chain */  \
          float K2   = FAST_EXP2(fmaf(eK, lq, cK2)); /* issue second */        \
          float X    = fmaxf(0.5f - t, 0.0f);                                  \
          float KX2  = K2 * X;                                                 \
          float A    = K2 - KX2;                                               \
          float rD   = FAST_RCP(A + DT_SUB_F);                                 \
          float num  = fmaf(A, q, fmaf(KX2, iomti, inn0));                     \
          q = fmaxf(num * rD, 0.0f);                                           \
        }                                                                      \
        _Pragma("unroll")                                                      \
        for (int s = 1; s < 4; ++s) {   /* substeps 1..3: io == inflow */      \
          const float inn = fmaf(-DT_SUB_F, q, dti); /* off-chain, pre-log2 */ \
          float Qref = fmaxf(fmaf(q, 1.0f/3.0f, t23), EPS_F);                  \
          float lq   = FAST_LOG2(Qref);                                        \
          float t    = FAST_EXP2(fmaf(et, lq, ct));  /* issue FIRST: chain */  \
          float K2   = FAST_EXP2(fmaf(eK, lq, cK2)); /* issue second */        \
          float X    = fmaxf(0.5f - t, 0.0f);                                  \
          float A    = K2 - K2 * X;                                            \
          float rD   = FAST_RCP(A + DT_SUB_F);                                 \
          float num  = fmaf(A, q, inn);              /* +DT*(2ti-q) */         \
          q = fmaxf(num * rD, 0.0f);                                           \
        }                                                                      \
        Q = q; Ip = inflow;                                                    \
                                                                               \
        float ps = pair_sum(q);          /* DPP, branchless, always */         \
        qs[j] = hasCons ? ps : q;        /* uniform select */                  \
      }

// ---------------------------------------------------------------------------
// One batch body (textual macro; banks substitute as plain array names).
// Structure is exact v14 (best measured: 556us).
// ---------------------------------------------------------------------------
#define MC_BODY(BI, latC, pendC, latN, pendN)                                  \
  {                                                                            \
    const int bi = (BI);                                                       \
    const int tb = bi * B;                                                     \
    /* clamped next-batch time base: last body harmlessly re-reads last batch*/\
    const int tbn = (tb + B < T_STEPS) ? (tb + B) : (T_STEPS - B);             \
                                                                               \
    /* ---- poll consumer progress early (non-blocking) ---- */                \
    int pfCons = -0x40000000;                                                  \
    const int need = (bi - slotsB + 1) * B;                                    \
    if (hasCons && bi >= slotsB && cachedCons < need) {                        \
      int v0 = ATOMIC_LD_RLX(&prog[c0i]);                                      \
      int v1 = (c1i == c0i) ? v0 : ATOMIC_LD_RLX(&prog[c1i]);                  \
      pfCons = (v0 < v1) ? v0 : v1;                                            \
    }                                                                          \
                                                                               \
    /* ---- verify CURRENT batch tags (prefetched mid-previous body) ----- */  \
    /* Steady state: fresh -> scan passes, zero reloads. Backstop: whole- */   \
    /* batch parallel reload + rescan (one round-trip per retry).         */   \
    if (hasProd) {                                                             \
      const unsigned long long* upC =                                          \
          ringUp + (size_t)(bi & sBm1) * upSlotSz + e;                         \
      unsigned mism = 0;                                                       \
      _Pragma("unroll")                                                        \
      for (int j = 0; j < B; ++j)                                              \
        mism |= ((unsigned)(pendC[j] >> 32) ^ (unsigned)(tb + j + 1));         \
      int spin = 0;                                                            \
      while (__builtin_expect(mism != 0u, 0)) {                                \
        _Pragma("unroll")                                                      \
        for (int j = 0; j < B; ++j)                                            \
          pendC[j] = ATOMIC_LD_RLX(upC + (size_t)j * size);                    \
        mism = 0;                                                              \
        _Pragma("unroll")                                                      \
        for (int j = 0; j < B; ++j)                                            \
          mism |= ((unsigned)(pendC[j] >> 32) ^ (unsigned)(tb + j + 1));       \
        if (mism && (((++spin) & 15) == 0)) __builtin_amdgcn_s_sleep(1);       \
      }                                                                        \
    }                                                                          \
                                                                               \
    /* ================= giant branchless BB, half 0 ================= */      \
    float qs[B];                                                               \
    {                                                                          \
      const size_t nbBase = (size_t)tbn * NR_TOTAL + (size_t)rr;               \
      _Pragma("unroll")                                                        \
      for (int j = 0; j < B; ++j)                                              \
        latN[j] = lat[nbBase + (size_t)j * NR_TOTAL];                          \
      MC_MATH_LOOP(0, B/2, latC, pendC)                                        \
                                                                               \
      /* ---- mid-body: prefetch NEXT batch ring (fresh in steady state; */    \
      /* ~B/2 steps of math ahead of use covers the MALL flight).        */    \
      /* Unconditional: level-0 reads are harmless in-bounds garbage,    */    \
      /* masked by prodMask; keeps this whole region one BB.             */    \
      {                                                                        \
        const unsigned long long* upN =                                        \
            ringUp + (size_t)((bi + 1) & sBm1) * upSlotSz + e;                 \
        _Pragma("unroll")                                                      \
        for (int j = 0; j < B; ++j)                                            \
          pendN[j] = ATOMIC_LD_RLX(upN + (size_t)j * size);                    \
      }                                                                        \
                                                                               \
      MC_MATH_LOOP(B/2, B, latC, pendC)                                        \
    }                                                                          \
    /* ================= end giant BB ================= */                     \
                                                                               \
    /* ---- back-pressure, then store the batch ---- */                        \
    if (hasCons) {                                                             \
      if (bi >= slotsB && cachedCons < need) {                                 \
        if (pfCons >= need) {                                                  \
          cachedCons = pfCons;                                                 \
        } else {                                                               \
          int spin = 0;                                                        \
          for (;;) {                                                           \
            int v0 = ATOMIC_LD_RLX(&prog[c0i]);                                \
            int v1 = (c1i == c0i) ? v0 : ATOMIC_LD_RLX(&prog[c1i]);            \
            int m  = (v0 < v1) ? v0 : v1;                                      \
            if (m >= need) { cachedCons = m; break; }                          \
            if (((++spin) & 63) == 0) __builtin_amdgcn_s_sleep(1);             \
          }                                                                    \
        }                                                                      \
      }                                                                        \
      if (validT && ((tid & 1) == 0)) {                                        \
        unsigned long long* st =                                               \
            ringMy + (size_t)(bi & sBm1) * mySlotSz + (e >> 1);                \
        _Pragma("unroll")                                                      \
        for (int j = 0; j < B; ++j) {                                          \
          unsigned long long v =                                               \
              ((unsigned long long)(unsigned)(tb + j + 1) << 32) |             \
              (unsigned long long)__float_as_uint(qs[j]);                      \
          ATOMIC_ST_RLX(st + (size_t)j * halfSize, v);                         \
        }                                                                      \
      }                                                                        \
    } else if (tid == 0) {                                                     \
      _Pragma("unroll")                                                        \
      for (int j = 0; j < B; ++j)                                              \
        out[tb + j] = qs[j];                                                   \
    }                                                                          \
                                                                               \
    /* ---- publish per-wave consumed progress ---- */                         \
    if (waveLead) {                                                            \
      int pubv = tb + B;                                                       \
      __asm__ volatile("" : "+v"(pubv) : "v"(Q));  /* orders after reads */    \
      ATOMIC_ST_RLX(&prog[myCtr], pubv);                                       \
    }                                                                          \
  }

template<int B>
__global__ __launch_bounds__(256, 1)
void mc_route_pipe17(const float* __restrict__ lat,
                     const float* __restrict__ logn,
                     const float* __restrict__ len,
                     const float* __restrict__ slope,
                     const float* __restrict__ wcoef,
                     const float* __restrict__ wexp,
                     const float* __restrict__ dcoef,
                     const float* __restrict__ dexp,
                     float* __restrict__ out,
                     int* __restrict__ prog,
                     unsigned long long* __restrict__ ring,
                     int slotsB)
{
    const int bid = blockIdx.x;
    const int tid = threadIdx.x;

    int lvl = 0;
#pragma unroll
    for (int l = 1; l < N_LEVELS; ++l)
        if (bid >= kBlkStart[l]) lvl = l;

    const int  bl     = bid - kBlkStart[lvl];
    const int  epb    = kEpb[lvl];
    const int  size   = kSize[lvl];
    const bool validT = (tid < epb);
    const int  e      = bl * epb + (validT ? tid : (epb - 1));
    const int  rr     = kOffL[lvl] + e;

    // -------- per-reach constants (chain-fused form, v5-verified) ----------
    const float dx      = len[rr];
    const float S       = slope[rr];
    const float sqrtS_n = sqrtf(S) * expf(-logn[rr]);        // sqrt(S)/n
    const float de23    = 0.66666667f * dexp[rr];
    const float l2dc    = log2f(dcoef[rr]);
    const float l2base  = log2f(0.6f / sqrtS_n) - 0.66666667f * l2dc;
    const float eK      = -de23;
    const float cK2     = log2f(2.0f * dx) + l2base;
    const float et      = 1.0f - de23 - wexp[rr];
    const float ct      = log2f(0.5f / (S * dx)) + l2base - log2f(wcoef[rr]);

    // -------- pipeline wiring ----------------------------------------------
    const bool hasProd = (lvl > 0);
    const bool hasCons = (lvl < N_LEVELS - 1);
    const unsigned prodMask = hasProd ? 0xFFFFFFFFu : 0u;
    const int  SBB     = slotsB * B;
    const int  sBm1    = slotsB - 1;
    const unsigned long long* ringUp = hasProd ? ring + (size_t)kOffH[lvl-1] * SBB : ring;
    unsigned long long*       ringMy = hasCons ? ring + (size_t)kOffH[lvl]   * SBB : ring;
    const int halfSize = size >> 1;
    const int upSlotSz = size * B;
    const int mySlotSz = halfSize * B;

    int c0i = 0, c1i = 0;
    if (hasCons) {
        const int ceLo = (bl * epb) >> 1;
        const int ceHi = ((bl + 1) * epb - 1) >> 1;
        const int epbN = kEpb[lvl+1];
        const int cb   = kBlkStart[lvl+1] + ceLo / epbN;
        const int le0  = ceLo - (ceLo / epbN) * epbN;
        const int le1  = ceHi - (ceHi / epbN) * epbN;
        c0i = (cb * 4 + (le0 >> 6)) * CTR_STRIDE;
        c1i = (cb * 4 + (le1 >> 6)) * CTR_STRIDE;
    }
    const int  myCtr    = (bid * 4 + (tid >> 6)) * CTR_STRIDE;
    const bool waveLead = ((tid & 63) == 0);

    float Q = 0.0f, Ip = 0.0f;
    int cachedCons = -0x40000000;

    float latA[B], latB[B];
    unsigned long long pendA[B], pendB[B];

    // -------- prologue: load batch 0 into bank A ---------------------------
#pragma unroll
    for (int j = 0; j < B; ++j)
        latA[j] = lat[(size_t)j * NR_TOTAL + rr];
    if (hasProd) {
#pragma unroll
        for (int j = 0; j < B; ++j)
            pendA[j] = ATOMIC_LD_RLX(ringUp + (size_t)j * size + e);
    } else {
#pragma unroll
        for (int j = 0; j < B; ++j) { pendA[j] = 0; pendB[j] = 0; }
    }

    // 2x-unrolled batch loop, ping-pong banks (no swap movs, no pointers)
    for (int bb = 0; bb < T_STEPS / B; bb += 2) {
        MC_BODY(bb,     latA, pendA, latB, pendB);
        MC_BODY(bb + 1, latB, pendB, latA, pendA);
    }
}

extern "C" void kernel_launch(void* const* d_in, const int* in_sizes, int n_in,
                              void* d_out, int out_size, void* d_ws, size_t ws_size,
                              hipStream_t stream) {
    const float* lat   = (const float*)d_in[0];
    const float* logn  = (const float*)d_in[1];
    const float* len   = (const float*)d_in[2];
    const float* slope = (const float*)d_in[3];
    const float* wc    = (const float*)d_in[4];
    const float* we    = (const float*)d_in[5];
    const float* dc    = (const float*)d_in[6];
    const float* de    = (const float*)d_in[7];
    float* out = (float*)d_out;

    int* prog = (int*)d_ws;
    unsigned long long* ring = (unsigned long long*)((char*)d_ws + RING_BYTE_OFF);

    auto needBytes = [](int Bv, int Sv) {
        return (size_t)RING_BYTE_OFF + (size_t)8191 * 8 * Bv * Sv;
    };

    if (needBytes(16, 8) <= ws_size) {
        mc_route_pipe17<16><<<NBLOCKS, 256, 0, stream>>>(lat, logn, len, slope, wc, we, dc, de,
                                                         out, prog, ring, 8);
    } else if (needBytes(16, 4) <= ws_size) {
        mc_route_pipe17<16><<<NBLOCKS, 256, 0, stream>>>(lat, logn, len, slope, wc, we, dc, de,
                                                         out, prog, ring, 4);
    } else if (needBytes(16, 2) <= ws_size) {
        mc_route_pipe17<16><<<NBLOCKS, 256, 0, stream>>>(lat, logn, len, slope, wc, we, dc, de,
                                                         out, prog, ring, 2);
    } else if (needBytes(8, 4) <= ws_size) {
        mc_route_pipe17<8><<<NBLOCKS, 256, 0, stream>>>(lat, logn, len, slope, wc, we, dc, de,
                                                        out, prog, ring, 4);
    } else {
        mc_route_pipe17<8><<<NBLOCKS, 256, 0, stream>>>(lat, logn, len, slope, wc, we, dc, de,
                                                        out, prog, ring, 2);
    }
}